// Round 4
// baseline (2051.017 us; speedup 1.0000x reference)
//
#include <hip/hip_runtime.h>

// DFPS: density-weighted Manhattan furthest point sampling.
// points:   [B, N, 3] f32   (B=4, N=8192 fixed by the problem)
// features: [B, C, N] f32   (unused)
// npoint:   int scalar (device, d_in[2])
// out:      [B, npoint] int32 indices

#define NPTS 8192
#define DENS_BLOCK 256
#define FPS_THREADS 512
#define FPS_P 16   // FPS_THREADS * FPS_P == NPTS

// ---------------- density ----------------
// One pass, no split/atomics: writes penalty = 1/count directly.

__global__ void dfps_density_kernel(const float* __restrict__ pts,
                                    float* __restrict__ pen, int N) {
#pragma clang fp contract(off)
    const float R2 = (float)(0.4 * 0.4);  // matches JAX scalar promotion
    const int b = blockIdx.y;
    const int i = blockIdx.x * blockDim.x + threadIdx.x;
    const float* P = pts + (size_t)b * N * 3;

    __shared__ float sx[DENS_BLOCK], sy[DENS_BLOCK], sz[DENS_BLOCK];

    const float px = P[i * 3 + 0], py = P[i * 3 + 1], pz = P[i * 3 + 2];

    int cnt = 0;
    for (int t0 = 0; t0 < N; t0 += DENS_BLOCK) {
        int j = t0 + threadIdx.x;
        __syncthreads();
        sx[threadIdx.x] = P[j * 3 + 0];
        sy[threadIdx.x] = P[j * 3 + 1];
        sz[threadIdx.x] = P[j * 3 + 2];
        __syncthreads();
#pragma unroll 4
        for (int jj = 0; jj < DENS_BLOCK; ++jj) {
            float dx = px - sx[jj];
            float dy = py - sy[jj];
            float dz = pz - sz[jj];
            float d2 = dx * dx;      // contract(off): numpy rounding order
            d2 = d2 + dy * dy;
            d2 = d2 + dz * dz;
            cnt += (d2 <= R2) ? 1 : 0;
        }
    }
    pen[(size_t)b * N + i] = 1.0f / (float)cnt;
}

// ---------------- FPS ----------------

// u64 max across the 64-lane wave via DPP (VALU pipe, no LDS round-trips).
// Result valid in lane 63.
#define DPP_STEP(ctrl, rmask)                                                   \
    {                                                                           \
        unsigned int nlo = (unsigned int)__builtin_amdgcn_update_dpp(           \
            0, (int)klo, (ctrl), (rmask), 0xF, false);                          \
        unsigned int nhi = (unsigned int)__builtin_amdgcn_update_dpp(           \
            0, (int)khi, (ctrl), (rmask), 0xF, false);                          \
        unsigned long long o = ((unsigned long long)nhi << 32) | nlo;           \
        unsigned long long c = ((unsigned long long)khi << 32) | klo;           \
        if (o > c) { klo = nlo; khi = nhi; }                                    \
    }

__global__ void __launch_bounds__(FPS_THREADS, 1)
dfps_fps_kernel(const float* __restrict__ pts,
                const float* __restrict__ penalty,
                const int* __restrict__ npoint_p,
                int* __restrict__ out, int N) {
#pragma clang fp contract(off)
    const int b = blockIdx.x;
    const int tid = threadIdx.x;
    const int lane = tid & 63;
    const int npoint = *npoint_p;
    const float* Pb = pts + (size_t)b * N * 3;
    const float* pen = penalty + (size_t)b * N;
    const int base = tid * FPS_P;

    // Coordinate table in LDS (float4: x,y,z,unused) -> one b128 winner fetch.
    __shared__ float4 tab[NPTS];                 // 128 KiB
    // Triple-buffered block-winner slot, reduced via ds_max_u64.
    // Body t: atomicMax into slot[t%3] (pre-barrier), read slot[t%3]
    // (post-barrier), zero slot[(t+1)%3] (pre-barrier). Every conflicting
    // access pair is separated by at least one __syncthreads().
    __shared__ unsigned long long slot[3];

    // Per-thread state in registers.
    float x[FPS_P], y[FPS_P], z[FPS_P], md[FPS_P], pw[FPS_P];
    unsigned int lo[FPS_P];  // key low words: N-1-idx (min-idx tiebreak)
#pragma unroll
    for (int k = 0; k < FPS_P; ++k) {
        int idx = base + k;
        x[k] = Pb[idx * 3 + 0];
        y[k] = Pb[idx * 3 + 1];
        z[k] = Pb[idx * 3 + 2];
        md[k] = 1e10f;
        pw[k] = pen[idx];
        lo[k] = (unsigned int)(N - 1 - idx);
        tab[idx] = make_float4(x[k], y[k], z[k], 0.f);
    }
    if (tid == 0) { slot[0] = 0ull; slot[2] = 0ull; }  // slot[1] zeroed in body 0
    __syncthreads();

    int cur = 0;
    float cx = Pb[0], cy = Pb[1], cz = Pb[2];

    for (int t = 0; t < npoint; ++t) {
        if (tid == 0) {
            out[(size_t)b * npoint + t] = cur;
            slot[(t + 1) % 3] = 0ull;  // safe: last read was before barrier t-1
        }

        // Distance update + u64 argmax keys; 4 independent chains for ILP.
        unsigned long long ck0 = 0ull, ck1 = 0ull, ck2 = 0ull, ck3 = 0ull;
#pragma unroll
        for (int k = 0; k < FPS_P; ++k) {
            // w=[1,1,2]; fmaf(2,|dz|,s) == s + 2*|dz| bitwise (2*|dz| exact)
            float d = fabsf(x[k] - cx) + fabsf(y[k] - cy);
            d = fmaf(2.0f, fabsf(z[k] - cz), d);
            float m = fminf(md[k], d);
            md[k] = m;
            float v = m * pw[k];  // v >= 0 -> float bits order == uint order
            unsigned long long key =
                ((unsigned long long)__float_as_uint(v) << 32) | lo[k];
            if ((k & 3) == 0)      { if (key > ck0) ck0 = key; }
            else if ((k & 3) == 1) { if (key > ck1) ck1 = key; }
            else if ((k & 3) == 2) { if (key > ck2) ck2 = key; }
            else                   { if (key > ck3) ck3 = key; }
        }
        unsigned long long ka = ck0 > ck1 ? ck0 : ck1;
        unsigned long long kb = ck2 > ck3 ? ck2 : ck3;
        unsigned long long best = ka > kb ? ka : kb;

        // Wave64 u64 max via DPP: row_shr 1/2/4/8, then row_bcast 15/31.
        unsigned int klo = (unsigned int)best;
        unsigned int khi = (unsigned int)(best >> 32);
        DPP_STEP(0x111, 0xF)  // row_shr:1
        DPP_STEP(0x112, 0xF)  // row_shr:2
        DPP_STEP(0x114, 0xF)  // row_shr:4
        DPP_STEP(0x118, 0xF)  // row_shr:8
        DPP_STEP(0x142, 0xA)  // row_bcast:15 -> rows 1,3
        DPP_STEP(0x143, 0xC)  // row_bcast:31 -> rows 2,3

        if (lane == 63) {
            unsigned long long wk = ((unsigned long long)khi << 32) | klo;
            atomicMax(&slot[t % 3], wk);  // ds_max_u64
        }
        __syncthreads();  // single barrier per iteration

        unsigned long long bk = slot[t % 3];
        cur = (N - 1) - (int)(unsigned int)(bk & 0xFFFFFFFFull);
        float4 c = tab[cur];  // uniform address -> LDS broadcast read
        cx = c.x;
        cy = c.y;
        cz = c.z;
    }
}

extern "C" void kernel_launch(void* const* d_in, const int* in_sizes, int n_in,
                              void* d_out, int out_size, void* d_ws, size_t ws_size,
                              hipStream_t stream) {
    const float* points  = (const float*)d_in[0];
    const int*   npoint  = (const int*)d_in[2];
    int* out = (int*)d_out;

    const int B = 4;
    const int N = in_sizes[0] / (B * 3);  // 8192
    float* penalty = (float*)d_ws;        // B*N floats = 128 KiB

    dim3 dgrid(N / DENS_BLOCK, B);
    dfps_density_kernel<<<dgrid, DENS_BLOCK, 0, stream>>>(points, penalty, N);

    dfps_fps_kernel<<<B, FPS_THREADS, 0, stream>>>(points, penalty, npoint, out, N);
}